// Round 1
// baseline (666.979 us; speedup 1.0000x reference)
//
#include <hip/hip_runtime.h>
#include <math.h>

// ---------------- degree histogram ----------------
__global__ void hist_kernel(const int* __restrict__ dst, int* __restrict__ counts, int E) {
    int e = blockIdx.x * blockDim.x + threadIdx.x;
    if (e < E) atomicAdd(&counts[dst[e]], 1);
}

__global__ void dinv_kernel(const int* __restrict__ counts, float* __restrict__ dinv, int n) {
    int i = blockIdx.x * blockDim.x + threadIdx.x;
    if (i < n) dinv[i] = rsqrtf((float)counts[i] + 1.0f);  // +1 self-loop; always > 0
}

// ---------------- exclusive scan (3 kernels) ----------------
// scan1: each block scans a 1024-element chunk (256 threads x 4), writes local
// exclusive scan to rowptr and the chunk total to partials[chunk].
__global__ void scan1_kernel(const int* __restrict__ counts, int* __restrict__ rowptr,
                             int* __restrict__ partials, int n) {
    __shared__ int tsum[256];
    int chunk = blockIdx.x;
    int base = chunk * 1024;
    int t = threadIdx.x;
    int v[4];
    int s = 0;
    #pragma unroll
    for (int j = 0; j < 4; ++j) {
        int idx = base + t * 4 + j;
        v[j] = (idx < n) ? counts[idx] : 0;
        s += v[j];
    }
    tsum[t] = s;
    __syncthreads();
    for (int off = 1; off < 256; off <<= 1) {
        int add = (t >= off) ? tsum[t - off] : 0;
        __syncthreads();
        tsum[t] += add;
        __syncthreads();
    }
    if (t == 255) partials[chunk] = tsum[255];
    int run = (t == 0) ? 0 : tsum[t - 1];
    #pragma unroll
    for (int j = 0; j < 4; ++j) {
        int idx = base + t * 4 + j;
        if (idx < n) rowptr[idx] = run;
        run += v[j];
    }
}

// scan2: single block, exclusive scan of <=128 chunk partials in place.
__global__ void scan2_kernel(int* __restrict__ partials, int nch) {
    __shared__ int s[128];
    int t = threadIdx.x;  // blockDim = 128
    s[t] = (t < nch) ? partials[t] : 0;
    __syncthreads();
    for (int off = 1; off < 128; off <<= 1) {
        int add = (t >= off) ? s[t - off] : 0;
        __syncthreads();
        s[t] += add;
        __syncthreads();
    }
    if (t < nch) partials[t] = (t == 0) ? 0 : s[t - 1];
}

// scan3: add chunk offsets; initialize cursor = rowptr.
__global__ void scan3_kernel(int* __restrict__ rowptr, const int* __restrict__ partials,
                             int* __restrict__ cursor, int n) {
    int i = blockIdx.x * blockDim.x + threadIdx.x;
    if (i < n) {
        int v = rowptr[i] + partials[i >> 10];
        rowptr[i] = v;
        cursor[i] = v;
    }
}

// fill: scatter src indices into CSR slots (cursor ends at row end).
__global__ void fill_kernel(const int* __restrict__ src, const int* __restrict__ dst,
                            int* __restrict__ cursor, int* __restrict__ csr_src, int E) {
    int e = blockIdx.x * blockDim.x + threadIdx.x;
    if (e < E) {
        int d = dst[e];
        int p = atomicAdd(&cursor[d], 1);
        csr_src[p] = src[e];
    }
}

// ---------------- dense matmul, fused dinv row-scale: G = (X @ W) * dinv ----------------
template <int K>
__global__ void matmul_scale64(const float* __restrict__ X, const float* __restrict__ W,
                               const float* __restrict__ dinv, float* __restrict__ G, int n) {
    __shared__ float w[K * 64];
    for (int i = threadIdx.x; i < K * 64; i += 256) w[i] = W[i];
    __syncthreads();
    int row = blockIdx.x * 4 + (threadIdx.x >> 6);
    int col = threadIdx.x & 63;
    if (row >= n) return;
    const float* xr = X + (size_t)row * K;
    float acc = 0.f;
    #pragma unroll
    for (int k = 0; k < K; ++k) acc = fmaf(xr[k], w[k * 64 + col], acc);
    G[(size_t)row * 64 + col] = acc * dinv[row];
}

// conv3 matmul: 64 -> 10, 16 lanes per row (cols 10..15 idle)
__global__ void matmul_scale10(const float* __restrict__ X, const float* __restrict__ W,
                               const float* __restrict__ dinv, float* __restrict__ G, int n) {
    __shared__ float w[64 * 10];
    for (int i = threadIdx.x; i < 640; i += 256) w[i] = W[i];
    __syncthreads();
    int row = blockIdx.x * 16 + (threadIdx.x >> 4);
    int col = threadIdx.x & 15;
    if (row >= n || col >= 10) return;
    const float* xr = X + (size_t)row * 64;
    float acc = 0.f;
    #pragma unroll
    for (int k = 0; k < 64; ++k) acc = fmaf(xr[k], w[k * 10 + col], acc);
    G[(size_t)row * 10 + col] = acc * dinv[row];
}

// ---------------- aggregation: out[d] = act(dinv[d]*(sum G[src] + G[d]) + b) [+resid] ----------------
template <bool RELU, bool RESID>
__global__ void agg64_kernel(const float* __restrict__ G, const int* __restrict__ rowptr,
                             const int* __restrict__ rowend, const int* __restrict__ csr_src,
                             const float* __restrict__ dinv, const float* __restrict__ bias,
                             const float* __restrict__ resid, float* __restrict__ out, int n) {
    int node = blockIdx.x * 4 + (threadIdx.x >> 6);
    int lane = threadIdx.x & 63;
    if (node >= n) return;
    float s = G[(size_t)node * 64 + lane];  // self-loop term
    int e = rowptr[node], end = rowend[node];
    for (; e < end; ++e) {
        int src = csr_src[e];
        s += G[(size_t)src * 64 + lane];
    }
    float v = s * dinv[node] + bias[lane];
    if (RELU) v = fmaxf(v, 0.f);
    if (RESID) v += resid[(size_t)node * 64 + lane];
    out[(size_t)node * 64 + lane] = v;
}

// final aggregation over 10 feats + fused log_softmax; 16 lanes per node
__global__ void agg10_lsm_kernel(const float* __restrict__ G, const int* __restrict__ rowptr,
                                 const int* __restrict__ rowend, const int* __restrict__ csr_src,
                                 const float* __restrict__ dinv, const float* __restrict__ bias,
                                 float* __restrict__ out, int n) {
    int node = blockIdx.x * 16 + (threadIdx.x >> 4);
    int lane = threadIdx.x & 15;
    if (node >= n) return;
    bool act = lane < 10;
    float s = act ? G[(size_t)node * 10 + lane] : 0.f;
    int e = rowptr[node], end = rowend[node];
    for (; e < end; ++e) {
        int src = csr_src[e];
        if (act) s += G[(size_t)src * 10 + lane];
    }
    float v = act ? (s * dinv[node] + bias[lane]) : -1e30f;
    float m = v;
    #pragma unroll
    for (int off = 8; off; off >>= 1) m = fmaxf(m, __shfl_xor(m, off, 16));
    float ex = act ? __expf(v - m) : 0.f;
    float sum = ex;
    #pragma unroll
    for (int off = 8; off; off >>= 1) sum += __shfl_xor(sum, off, 16);
    if (act) out[(size_t)node * 10 + lane] = v - m - __logf(sum);
}

extern "C" void kernel_launch(void* const* d_in, const int* in_sizes, int n_in,
                              void* d_out, int out_size, void* d_ws, size_t ws_size,
                              hipStream_t stream) {
    const float* x  = (const float*)d_in[0];
    const int*   ei = (const int*)d_in[1];
    const float* W1 = (const float*)d_in[2];
    const float* b1 = (const float*)d_in[3];
    const float* W2 = (const float*)d_in[4];
    const float* b2 = (const float*)d_in[5];
    const float* W3 = (const float*)d_in[6];
    const float* b3 = (const float*)d_in[7];
    float* out = (float*)d_out;

    const int N = in_sizes[0] / 13;
    const int E = in_sizes[1] / 2;
    const int* src = ei;
    const int* dst = ei + E;

    char* p = (char*)d_ws;
    auto alloc = [&](size_t bytes) -> void* {
        void* r = (void*)p;
        p += (bytes + 255) & ~(size_t)255;
        return r;
    };
    int*   counts   = (int*)alloc((size_t)N * 4);
    int*   rowptr   = (int*)alloc((size_t)N * 4);
    int*   cursor   = (int*)alloc((size_t)N * 4);
    int*   partials = (int*)alloc(512);
    int*   csr_src  = (int*)alloc((size_t)E * 4);
    float* dinv     = (float*)alloc((size_t)N * 4);
    float* G        = (float*)alloc((size_t)N * 64 * 4);
    float* x1       = (float*)alloc((size_t)N * 64 * 4);
    float* x2       = (float*)alloc((size_t)N * 64 * 4);

    hipMemsetAsync(counts, 0, (size_t)N * 4, stream);

    int eb = (E + 255) / 256;
    int nb = (N + 255) / 256;
    int nch = (N + 1023) / 1024;

    hist_kernel<<<eb, 256, 0, stream>>>(dst, counts, E);
    dinv_kernel<<<nb, 256, 0, stream>>>(counts, dinv, N);
    scan1_kernel<<<nch, 256, 0, stream>>>(counts, rowptr, partials, N);
    scan2_kernel<<<1, 128, 0, stream>>>(partials, nch);
    scan3_kernel<<<nb, 256, 0, stream>>>(rowptr, partials, cursor, N);
    fill_kernel<<<eb, 256, 0, stream>>>(src, dst, cursor, csr_src, E);

    int rb4 = (N + 3) / 4;
    int rb16 = (N + 15) / 16;

    // conv1: 13 -> 64, ReLU
    matmul_scale64<13><<<rb4, 256, 0, stream>>>(x, W1, dinv, G, N);
    agg64_kernel<true, false><<<rb4, 256, 0, stream>>>(G, rowptr, cursor, csr_src, dinv, b1, nullptr, x1, N);
    // conv2: 64 -> 64, ReLU + residual (x2 = relu(conv2) + x1)
    matmul_scale64<64><<<rb4, 256, 0, stream>>>(x1, W2, dinv, G, N);
    agg64_kernel<true, true><<<rb4, 256, 0, stream>>>(G, rowptr, cursor, csr_src, dinv, b2, x1, x2, N);
    // conv3: 64 -> 10 + log_softmax
    matmul_scale10<<<rb16, 256, 0, stream>>>(x2, W3, dinv, G, N);
    agg10_lsm_kernel<<<rb16, 256, 0, stream>>>(G, rowptr, cursor, csr_src, dinv, b3, out, N);
}

// Round 2
// 529.213 us; speedup vs baseline: 1.2603x; 1.2603x over previous
//
#include <hip/hip_runtime.h>
#include <math.h>

// ---------------- degree histogram ----------------
__global__ void hist_kernel(const int* __restrict__ dst, int* __restrict__ counts, int E) {
    int e = blockIdx.x * blockDim.x + threadIdx.x;
    if (e < E) atomicAdd(&counts[dst[e]], 1);
}

__global__ void dinv_kernel(const int* __restrict__ counts, float* __restrict__ dinv, int n) {
    int i = blockIdx.x * blockDim.x + threadIdx.x;
    if (i < n) dinv[i] = rsqrtf((float)counts[i] + 1.0f);  // +1 self-loop; always > 0
}

// ---------------- exclusive scan (3 kernels) ----------------
__global__ void scan1_kernel(const int* __restrict__ counts, int* __restrict__ rowptr,
                             int* __restrict__ partials, int n) {
    __shared__ int tsum[256];
    int chunk = blockIdx.x;
    int base = chunk * 1024;
    int t = threadIdx.x;
    int v[4];
    int s = 0;
    #pragma unroll
    for (int j = 0; j < 4; ++j) {
        int idx = base + t * 4 + j;
        v[j] = (idx < n) ? counts[idx] : 0;
        s += v[j];
    }
    tsum[t] = s;
    __syncthreads();
    for (int off = 1; off < 256; off <<= 1) {
        int add = (t >= off) ? tsum[t - off] : 0;
        __syncthreads();
        tsum[t] += add;
        __syncthreads();
    }
    if (t == 255) partials[chunk] = tsum[255];
    int run = (t == 0) ? 0 : tsum[t - 1];
    #pragma unroll
    for (int j = 0; j < 4; ++j) {
        int idx = base + t * 4 + j;
        if (idx < n) rowptr[idx] = run;
        run += v[j];
    }
}

__global__ void scan2_kernel(int* __restrict__ partials, int nch) {
    __shared__ int s[128];
    int t = threadIdx.x;  // blockDim = 128
    s[t] = (t < nch) ? partials[t] : 0;
    __syncthreads();
    for (int off = 1; off < 128; off <<= 1) {
        int add = (t >= off) ? s[t - off] : 0;
        __syncthreads();
        s[t] += add;
        __syncthreads();
    }
    if (t < nch) partials[t] = (t == 0) ? 0 : s[t - 1];
}

__global__ void scan3_kernel(int* __restrict__ rowptr, const int* __restrict__ partials,
                             int* __restrict__ cursor, int n) {
    int i = blockIdx.x * blockDim.x + threadIdx.x;
    if (i < n) {
        int v = rowptr[i] + partials[i >> 10];
        rowptr[i] = v;
        cursor[i] = v;
    }
}

__global__ void fill_kernel(const int* __restrict__ src, const int* __restrict__ dst,
                            int* __restrict__ cursor, int* __restrict__ csr_src, int E) {
    int e = blockIdx.x * blockDim.x + threadIdx.x;
    if (e < E) {
        int d = dst[e];
        int p = atomicAdd(&cursor[d], 1);
        csr_src[p] = src[e];
    }
}

// ---------------- conv1 pre-scale: xs[n,16] = x[n,13]*dinv[n], padded with 0 ----------------
__global__ void scale13_kernel(const float* __restrict__ x, const float* __restrict__ dinv,
                               float* __restrict__ xs, int n) {
    int i = blockIdx.x * blockDim.x + threadIdx.x;
    if (i >= n * 16) return;
    int node = i >> 4, c = i & 15;
    xs[i] = (c < 13) ? x[node * 13 + c] * dinv[node] : 0.f;
}

// ---------------- 16-wide aggregation (13 active): a1 = dinv[d]*(sum xs[src] + xs[d]) ----------------
__global__ void agg16_kernel(const float* __restrict__ xs, const int* __restrict__ rowptr,
                             const int* __restrict__ rowend, const int* __restrict__ csr_src,
                             const float* __restrict__ dinv, float* __restrict__ a1, int n) {
    int node = blockIdx.x * 16 + (threadIdx.x >> 4);
    int lane = threadIdx.x & 15;
    if (node >= n) return;
    float s = xs[(size_t)node * 16 + lane];
    int e0 = rowptr[node], end = rowend[node];
    for (int base = e0; base < end; base += 8) {
        #pragma unroll
        for (int j = 0; j < 8; ++j) {
            int idx = base + j;
            int sj = csr_src[idx < end ? idx : end - 1];
            float g = xs[(size_t)sj * 16 + lane];
            if (idx < end) s += g;
        }
    }
    a1[(size_t)node * 16 + lane] = s * dinv[node];
}

// ---------------- conv1 matmul: x1 = relu(a1 @ W1 + b1), K=13 (stride 16) ----------------
__global__ void matmul13_kernel(const float* __restrict__ a1, const float* __restrict__ W1,
                                const float* __restrict__ b1, float* __restrict__ x1, int n) {
    __shared__ float w[13 * 64];
    for (int i = threadIdx.x; i < 13 * 64; i += 256) w[i] = W1[i];
    __syncthreads();
    int row = blockIdx.x * 4 + (threadIdx.x >> 6);
    int col = threadIdx.x & 63;
    if (row >= n) return;
    const float* ar = a1 + (size_t)row * 16;
    float acc = b1[col];
    #pragma unroll
    for (int k = 0; k < 13; ++k) acc = fmaf(ar[k], w[k * 64 + col], acc);
    x1[(size_t)row * 64 + col] = fmaxf(acc, 0.f);
}

// ---------------- dense matmul, fused dinv row-scale: G = (X @ W) * dinv ----------------
__global__ void matmul_scale64(const float* __restrict__ X, const float* __restrict__ W,
                               const float* __restrict__ dinv, float* __restrict__ G, int n) {
    __shared__ float w[64 * 64];
    for (int i = threadIdx.x; i < 64 * 64; i += 256) w[i] = W[i];
    __syncthreads();
    int row = blockIdx.x * 4 + (threadIdx.x >> 6);
    int col = threadIdx.x & 63;
    if (row >= n) return;
    const float* xr = X + (size_t)row * 64;
    float acc = 0.f;
    #pragma unroll
    for (int k = 0; k < 64; ++k) acc = fmaf(xr[k], w[k * 64 + col], acc);
    G[(size_t)row * 64 + col] = acc * dinv[row];
}

// conv3 matmul: 64 -> 10, padded to 16 cols (pad cols written as 0)
__global__ void matmul_scale10(const float* __restrict__ X, const float* __restrict__ W,
                               const float* __restrict__ dinv, float* __restrict__ G, int n) {
    __shared__ float w[64 * 10];
    for (int i = threadIdx.x; i < 640; i += 256) w[i] = W[i];
    __syncthreads();
    int row = blockIdx.x * 16 + (threadIdx.x >> 4);
    int col = threadIdx.x & 15;
    if (row >= n) return;
    float r = 0.f;
    if (col < 10) {
        const float* xr = X + (size_t)row * 64;
        float acc = 0.f;
        #pragma unroll
        for (int k = 0; k < 64; ++k) acc = fmaf(xr[k], w[k * 10 + col], acc);
        r = acc * dinv[row];
    }
    G[(size_t)row * 16 + col] = r;
}

// ---------------- 64-wide aggregation: out = act(dinv[d]*(sum G[src] + G[d]) + b) [+resid] ----------------
template <bool RELU, bool RESID>
__global__ void agg64_kernel(const float* __restrict__ G, const int* __restrict__ rowptr,
                             const int* __restrict__ rowend, const int* __restrict__ csr_src,
                             const float* __restrict__ dinv, const float* __restrict__ bias,
                             const float* __restrict__ resid, float* __restrict__ out, int n) {
    // node is wave-uniform: force into SGPR so rowptr/csr_src become scalar loads
    int node = __builtin_amdgcn_readfirstlane(blockIdx.x * 4 + (int)(threadIdx.x >> 6));
    int lane = threadIdx.x & 63;
    if (node >= n) return;
    float s = G[(size_t)node * 64 + lane];  // self-loop term
    int e0 = rowptr[node], end = rowend[node];
    for (int base = e0; base < end; base += 8) {
        #pragma unroll
        for (int j = 0; j < 8; ++j) {
            int idx = base + j;
            int sj = csr_src[idx < end ? idx : end - 1];
            float g = G[(size_t)sj * 64 + lane];
            if (idx < end) s += g;
        }
    }
    float v = s * dinv[node] + bias[lane];
    if (RELU) v = fmaxf(v, 0.f);
    if (RESID) v += resid[(size_t)node * 64 + lane];
    out[(size_t)node * 64 + lane] = v;
}

// final aggregation over padded-16 feats + fused log_softmax; 16 lanes per node
__global__ void agg10_lsm_kernel(const float* __restrict__ G, const int* __restrict__ rowptr,
                                 const int* __restrict__ rowend, const int* __restrict__ csr_src,
                                 const float* __restrict__ dinv, const float* __restrict__ bias,
                                 float* __restrict__ out, int n) {
    int node = blockIdx.x * 16 + (threadIdx.x >> 4);
    int lane = threadIdx.x & 15;
    if (node >= n) return;
    bool act = lane < 10;
    float s = G[(size_t)node * 16 + lane];  // pad cols hold 0
    int e0 = rowptr[node], end = rowend[node];
    for (int base = e0; base < end; base += 8) {
        #pragma unroll
        for (int j = 0; j < 8; ++j) {
            int idx = base + j;
            int sj = csr_src[idx < end ? idx : end - 1];
            float g = G[(size_t)sj * 16 + lane];
            if (idx < end) s += g;
        }
    }
    float v = act ? (s * dinv[node] + bias[lane]) : -1e30f;
    float m = v;
    #pragma unroll
    for (int off = 8; off; off >>= 1) m = fmaxf(m, __shfl_xor(m, off, 16));
    float ex = act ? __expf(v - m) : 0.f;
    float sum = ex;
    #pragma unroll
    for (int off = 8; off; off >>= 1) sum += __shfl_xor(sum, off, 16);
    if (act) out[(size_t)node * 10 + lane] = v - m - __logf(sum);
}

extern "C" void kernel_launch(void* const* d_in, const int* in_sizes, int n_in,
                              void* d_out, int out_size, void* d_ws, size_t ws_size,
                              hipStream_t stream) {
    const float* x  = (const float*)d_in[0];
    const int*   ei = (const int*)d_in[1];
    const float* W1 = (const float*)d_in[2];
    const float* b1 = (const float*)d_in[3];
    const float* W2 = (const float*)d_in[4];
    const float* b2 = (const float*)d_in[5];
    const float* W3 = (const float*)d_in[6];
    const float* b3 = (const float*)d_in[7];
    float* out = (float*)d_out;

    const int N = in_sizes[0] / 13;
    const int E = in_sizes[1] / 2;
    const int* src = ei;
    const int* dst = ei + E;

    char* p = (char*)d_ws;
    auto alloc = [&](size_t bytes) -> void* {
        void* r = (void*)p;
        p += (bytes + 255) & ~(size_t)255;
        return r;
    };
    int*   counts   = (int*)alloc((size_t)N * 4);
    int*   rowptr   = (int*)alloc((size_t)N * 4);
    int*   cursor   = (int*)alloc((size_t)N * 4);
    int*   partials = (int*)alloc(512);
    int*   csr_src  = (int*)alloc((size_t)E * 4);
    float* dinv     = (float*)alloc((size_t)N * 4);
    float* G        = (float*)alloc((size_t)N * 64 * 4);  // also hosts xs, a1, G3 (time-shared)
    float* x1       = (float*)alloc((size_t)N * 64 * 4);
    float* x2       = (float*)alloc((size_t)N * 64 * 4);

    float* xs = G;               // [N,16] — dead once a1 built
    float* a1 = G + (size_t)N * 16;  // [N,16] — dead once x1 built
    float* G3 = G;               // [N,16] — reuses G2 space (dead after x2)

    hipMemsetAsync(counts, 0, (size_t)N * 4, stream);

    int eb = (E + 255) / 256;
    int nb = (N + 255) / 256;
    int nch = (N + 1023) / 1024;

    hist_kernel<<<eb, 256, 0, stream>>>(dst, counts, E);
    dinv_kernel<<<nb, 256, 0, stream>>>(counts, dinv, N);
    scan1_kernel<<<nch, 256, 0, stream>>>(counts, rowptr, partials, N);
    scan2_kernel<<<1, 128, 0, stream>>>(partials, nch);
    scan3_kernel<<<nb, 256, 0, stream>>>(rowptr, partials, cursor, N);
    fill_kernel<<<eb, 256, 0, stream>>>(src, dst, cursor, csr_src, E);

    int rb4 = (N + 3) / 4;
    int rb16 = (N + 15) / 16;
    int sb = (N * 16 + 255) / 256;

    // conv1: aggregate 13-wide FIRST (A·(XW) == (A·X)·W), then matmul
    scale13_kernel<<<sb, 256, 0, stream>>>(x, dinv, xs, N);
    agg16_kernel<<<rb16, 256, 0, stream>>>(xs, rowptr, cursor, csr_src, dinv, a1, N);
    matmul13_kernel<<<rb4, 256, 0, stream>>>(a1, W1, b1, x1, N);

    // conv2: 64 -> 64, ReLU + residual (x2 = relu(conv2) + x1)
    matmul_scale64<<<rb4, 256, 0, stream>>>(x1, W2, dinv, G, N);
    agg64_kernel<true, true><<<rb4, 256, 0, stream>>>(G, rowptr, cursor, csr_src, dinv, b2, x1, x2, N);

    // conv3: 64 -> 10 (padded 16) + log_softmax
    matmul_scale10<<<rb16, 256, 0, stream>>>(x2, W3, dinv, G3, N);
    agg10_lsm_kernel<<<rb16, 256, 0, stream>>>(G3, rowptr, cursor, csr_src, dinv, b3, out, N);
}